// Round 9
// baseline (9784.565 us; speedup 1.0000x reference)
//
#include <hip/hip_runtime.h>

typedef unsigned int u32;
typedef unsigned short u16;
typedef _Float16 half2_t __attribute__((ext_vector_type(2)));

#define TM 94          // T_MOD
#define NB 2           // batches per decoder block
#define DEC_NT 512     // 512-thread blocks: 2 independent barrier domains per CU

// ---------- helpers ----------
__device__ __forceinline__ float bf2f(u16 v){ return __builtin_bit_cast(float, ((u32)v)<<16); }
__device__ __forceinline__ float bflo(u32 v){ return __builtin_bit_cast(float, v<<16); }
__device__ __forceinline__ float bfhi(u32 v){ return __builtin_bit_cast(float, v & 0xffff0000u); }
__device__ __forceinline__ u32 f2bf_bits(float f){ u32 u=__builtin_bit_cast(u32,f); return (u + 0x7fffu + ((u>>16)&1u))>>16; }
__device__ __forceinline__ u32 packbf2(float a, float b){ return f2bf_bits(a) | (f2bf_bits(b)<<16); }
__device__ __forceinline__ u32 packh2(float a, float b){ half2_t h; h.x=(_Float16)a; h.y=(_Float16)b; return __builtin_bit_cast(u32,h); }
__device__ __forceinline__ float fdot2(u32 a, u32 b, float c){
  return __builtin_amdgcn_fdot2(__builtin_bit_cast(half2_t,a), __builtin_bit_cast(half2_t,b), c, false);
}
__device__ __forceinline__ float fast_rcp(float x){ return __builtin_amdgcn_rcpf(x); }
__device__ __forceinline__ float sigmoid_f(float x){ return fast_rcp(1.f + __expf(-x)); }
__device__ __forceinline__ float tanh_f(float x){ float e=__expf(2.f*x); return 1.f - 2.f*fast_rcp(e+1.f); }

// ---------- kernel 0: pack LSTM weights (WgT), Wd fragments (WdT2), conv weights (cwT2) ----------
// WgT[j][t] (uint4), j=0..15, t=h*512+g: h=0 wih row g (u32 k-idx u=4j+s, u<50 else 0),
//                                        h=1 whh row g (u<64).
// WdT2[i][t] (uint4), i=0..7, t=0..511: P1 fragment for thread t=(mw=t>>2, part=t&3),
//   u32 base u = part*32 + ((i+2*part)&7)*4 (bank rotation baked in). mw>=100 -> 0.
// cwT2[c][j][k] (float): conv weight transpose (contiguous block-uniform stream).
__global__ __launch_bounds__(256)
void prep_kernel(const float* __restrict__ wih, const float* __restrict__ whh,
                 const float* __restrict__ Wd, const float* __restrict__ cw,
                 uint4* __restrict__ WgT, uint4* __restrict__ WdT2,
                 float* __restrict__ cwT2)
{
  int idx = blockIdx.x*256 + threadIdx.x;   // 0..77311
  if (idx < 16384){
    int t = idx & 1023;
    int j = idx >> 10;
    int h = t >> 9, g = t & 511;
    u32 r[4];
    #pragma unroll
    for (int s=0;s<4;s++){
      int u = 4*j + s;
      u32 v = 0u;
      if (h==0){ if (u < 50) v = packh2(wih[g*100+2*u], wih[g*100+2*u+1]); }
      else     { if (u < 64) v = packh2(whh[g*128+2*u], whh[g*128+2*u+1]); }
      r[s]=v;
    }
    WgT[idx] = make_uint4(r[0],r[1],r[2],r[3]);
  } else if (idx < 20480){
    int idx2 = idx - 16384;                 // 0..4095
    int t = idx2 & 511;
    int i = idx2 >> 9;                      // 0..7
    int mw = t >> 2, part = t & 3;
    u32 r[4] = {0u,0u,0u,0u};
    if (mw < 100){
      int ii = (i + 2*part) & 7;
      const float* wd = Wd + mw*256 + 2*(part*32 + ii*4);
      #pragma unroll
      for (int k=0;k<4;k++) r[k] = packh2(wd[2*k], wd[2*k+1]);
    }
    WdT2[idx2] = make_uint4(r[0],r[1],r[2],r[3]);
  } else if (idx < 20480 + 56700){
    int idx2 = idx - 20480;                 // 0..56699
    int c = idx2 / 5670;
    int r = idx2 - c*5670;
    int j = r / 10;
    int k = r - j*10;
    cwT2[idx2] = cw[(size_t)(10*c + k)*567 + j];
  }
}

// ---------- kernel 1: conv + relu -> H (bf16) ----------
__global__ __launch_bounds__(128)
void conv_kernel(const float* __restrict__ enc, const float* __restrict__ cwT2,
                 const float* __restrict__ cb, u16* __restrict__ Hb)
{
  __shared__ float sE[8100];
  const int tid = threadIdx.x;
  const int b = blockIdx.y;
  const int chunk = blockIdx.x;      // 10 chunks of 10 m's
  const float* ep = enc + (size_t)b*8100;
  for (int i=tid;i<8100;i+=128) sE[i]=ep[i];
  __syncthreads();
  if (tid >= TM) return;
  const int t = tid;
  const int mo = chunk*10;
  const float* wb = cwT2 + chunk*5670;   // block-uniform, contiguous [j][10] stream
  float acc[10];
  #pragma unroll
  for (int k=0;k<10;k++) acc[k]=cb[mo+k];
  const float* e = sE + t*81;
  #pragma unroll 3
  for (int j=0;j<567;j++){
    float ev = e[j];
    const float* w = wb + j*10;
    #pragma unroll
    for (int k=0;k<10;k++) acc[k] += ev*w[k];
  }
  u32* out = (u32*)Hb + ((size_t)b*9400 + t*100 + mo)/2;
  #pragma unroll
  for (int k=0;k<5;k++) out[k] = packbf2(fmaxf(acc[2*k],0.f), fmaxf(acc[2*k+1],0.f));
}

// ---------- kernel 2: persistent decoder, NB=2, 512 threads, 2 blocks/CU ----------
// R9: 4 barriers/step (was 6). P3 deleted (no-max softmax: P2 writes exp(score),
// P4 self-normalizes via a 3rd shuffle accumulator). P6 merged into P5 via
// lane-group gate ownership g=(tid&3)*128+(tid>>2): the 4 gates of one (bi,p)
// live in 4 consecutive lanes -> shfl_xor(1,2) merge, no sg16 LDS round-trip.
// z d-part double-buffered (+512 B) so P5's in-phase d-write can't race d-reads.
// VGPR pool model (R0-R8 ledger): waves/SIMD = floor(256/VGPR) for wave64.
// VGPR 64 -> 4 waves/SIMD = 2 blocks/CU (the ceiling). Keep VGPR at 64:
// tripwire = OccupancyPercent ~24% means VGPR crept past 64.
// LDS layout (bytes), NB=2:
#define OFF_SHU 37600      // sHU [2][94][50] u32 bf16-pairs
#define OFF_SQ  75200      // sq16 u32[2][128]: q=[d|s] f16 pairs (P1)
#define OFF_SZ  76224      // sz u32[2][192]: c(50)+pad(14) @0 | d0 @64 | d1 @128
#define OFF_SVD 77760      // vd fp32 [100]
#define OFF_AB  78160      // sa f32[2][100]@0, sbeta f32[2][96]@800
#define DEC_LDS 79728      // 2 x ~80KB fits 160KB -> 2 blocks/CU

__global__ __launch_bounds__(DEC_NT) __attribute__((amdgpu_waves_per_eu(2, 4)))
void decoder_kernel(const u16* __restrict__ Hb, const float* __restrict__ Ud,
                    const float* __restrict__ vd,
                    const uint4* __restrict__ WgT, const uint4* __restrict__ WdT2,
                    const float* __restrict__ bih, const float* __restrict__ bhh,
                    float* __restrict__ dT, float* __restrict__ cLast)
{
  extern __shared__ char smem[];
  u16*      sH   = (u16*)smem;                       // [2][94][100] bf16
  u16*      sHU  = (u16*)(smem + OFF_SHU);
  u32*      sq32 = (u32*)(smem + OFF_SQ);
  _Float16* sq16 = (_Float16*)(smem + OFF_SQ);
  u32*      sz32 = (u32*)(smem + OFF_SZ);
  float*    svd  = (float*)(smem + OFF_SVD);
  float*    sa   = (float*)(smem + OFF_AB);          // live P1->P2
  float*    sbeta= (float*)(smem + OFF_AB + 800);    // e-values, live P2->P4

  const int tid = threadIdx.x;
  const int b0 = blockIdx.x * NB;

  // stage H (2 batches): 2350 uint4
  {
    const uint4* src = (const uint4*)(Hb + (size_t)b0*9400);
    uint4* dst = (uint4*)sH;
    for (int i=tid;i<2350;i+=DEC_NT) dst[i]=src[i];
  }
  if (tid < 100) svd[tid] = vd[tid];
  for (int i=tid;i<NB*128;i+=DEC_NT) sq32[i]=0u;
  for (int i=tid;i<NB*192;i+=DEC_NT) sz32[i]=0u;
  __syncthreads();

  // HU[bi][t][k] = sum_m H[bi][t][m] * Ud[k][m]
  for (int idx=tid; idx<4700; idx+=DEC_NT){
    int kq = idx/188;                 // k-quad 0..24
    int r  = idx - kq*188;            // 0..187
    int bi = r/94;
    int t  = r - 94*bi;
    const u32* hrow = (const u32*)sH + bi*4700 + t*50;
    const float* ud0 = Ud + (kq*4+0)*100;
    const float* ud1 = Ud + (kq*4+1)*100;
    const float* ud2 = Ud + (kq*4+2)*100;
    const float* ud3 = Ud + (kq*4+3)*100;
    float c0=0.f,c1=0.f,c2=0.f,c3=0.f;
    #pragma unroll 5
    for (int mq=0; mq<25; mq++){
      uint2 hp = *(const uint2*)(hrow + mq*2);
      float h0=bflo(hp.x), h1=bfhi(hp.x), h2=bflo(hp.y), h3=bfhi(hp.y);
      float4 u0 = *(const float4*)(ud0 + mq*4);
      float4 u1 = *(const float4*)(ud1 + mq*4);
      float4 u2 = *(const float4*)(ud2 + mq*4);
      float4 u3 = *(const float4*)(ud3 + mq*4);
      c0 += h0*u0.x + h1*u0.y + h2*u0.z + h3*u0.w;
      c1 += h0*u1.x + h1*u1.y + h2*u1.z + h3*u1.w;
      c2 += h0*u2.x + h1*u2.y + h2*u2.z + h3*u2.w;
      c3 += h0*u3.x + h1*u3.y + h2*u3.z + h3*u3.w;
    }
    u32* dst = (u32*)sHU + bi*4700 + t*50 + kq*2;
    dst[0] = packbf2(c0,c1);
    dst[1] = packbf2(c2,c3);
  }
  __syncthreads();

  // P1 geometry: 4 lanes per Wd row, fragments PERSISTENT in registers (32 VGPR)
  const int mw = tid>>2, part = tid&3;
  uint4 wv[8];
  if (mw < 100){
    #pragma unroll
    for (int i=0;i<8;i++) wv[i] = WdT2[i*512 + tid];
  }
  // P5: lane-group gate ownership: lanes (p,gid=0..3) own gate rows gid*128+p.
  const int p5 = tid>>2, gid = tid&3;
  const int g5 = gid*128 + p5;
  const float biasg = bih[g5] + bhh[g5];
  const uint4* wp0 = WgT + g5;          // wih rows (h=0 region)
  const uint4* wp1 = WgT + 512 + g5;    // whh rows (h=1 region)

  float s_reg = 0.f;                 // LSTM cell state for lane's batch (gid>>1)

  #pragma unroll 1
  for (int step=0; step<TM; step++){
    // P1: a[bi][m] = q[bi] . Wd[m]  (4 lanes per row, rotated chunks for banks)
    if (mw < 100){
      #pragma unroll 1
      for (int bi=0;bi<NB;bi++){
        const u32* qb = sq32 + bi*128 + part*32;
        float a0=0.f, a1=0.f;
        #pragma unroll
        for (int i=0;i<8;i++){
          int ii = (i+2*part)&7;
          uint4 qv = *(const uint4*)(qb + ii*4);
          a0 = fdot2(wv[i].x, qv.x, a0);
          a1 = fdot2(wv[i].y, qv.y, a1);
          a0 = fdot2(wv[i].z, qv.z, a0);
          a1 = fdot2(wv[i].w, qv.w, a1);
        }
        float acc = a0+a1;
        acc += __shfl_xor(acc,1);
        acc += __shfl_xor(acc,2);
        if (part==0) sa[bi*100+mw]=acc;
      }
    }
    __syncthreads();
    // P2: e[bi][t] = exp(sum_m vd[m]*tanh(a+HU)); no max-subtract (|score|<~4,
    // bounded by sum|vd|); P4 normalizes. 2 threads/row.
    if (tid < NB*188){
      int row = tid>>1, th = tid&1;
      int bi = row/94;
      int t  = row - 94*bi;
      const uint4* hu4 = (const uint4*)((const u32*)sHU + bi*4700 + t*50 + th*24);
      const float4* ap = (const float4*)(sa + bi*100) + th*12;
      const float4* vp = (const float4*)svd + th*12;
      float acc=0.f;
      #pragma unroll
      for (int c=0;c<6;c++){
        uint4 h4 = hu4[c];
        float4 a0 = ap[2*c], a1 = ap[2*c+1];
        float4 v0 = vp[2*c], v1 = vp[2*c+1];
        acc += v0.x*tanh_f(a0.x + bflo(h4.x));
        acc += v0.y*tanh_f(a0.y + bfhi(h4.x));
        acc += v0.z*tanh_f(a0.z + bflo(h4.y));
        acc += v0.w*tanh_f(a0.w + bfhi(h4.y));
        acc += v1.x*tanh_f(a1.x + bflo(h4.z));
        acc += v1.y*tanh_f(a1.y + bfhi(h4.z));
        acc += v1.z*tanh_f(a1.z + bflo(h4.w));
        acc += v1.w*tanh_f(a1.w + bfhi(h4.w));
      }
      if (th){ // tail m=96..99
        uint2 ht = *(const uint2*)((const u32*)hu4 + 24);
        float4 a = ap[12]; float4 v = vp[12];
        acc += v.x*tanh_f(a.x + bflo(ht.x));
        acc += v.y*tanh_f(a.y + bfhi(ht.x));
        acc += v.z*tanh_f(a.z + bflo(ht.y));
        acc += v.w*tanh_f(a.w + bfhi(ht.y));
      }
      acc += __shfl_xor(acc,1);
      if (!th) sbeta[bi*96+t]=__expf(acc);
    }
    __syncthreads();
    // P4: c[bi][m] = (sum_t e_t*H)/(sum_t e_t); 4 threads per (bi,m-pair);
    // the asum shuffle tree replaces the old P3 softmax phase.
    if (tid < NB*200){
      int bi = tid/200;
      int r  = tid - 200*bi;
      int mp = r>>2, th = r&3;
      int tstart = (th<2) ? th*24 : 48+(th-2)*23;
      const float* bp = sbeta + bi*96 + tstart;
      const u32* hp = (const u32*)sH + bi*4700 + tstart*50 + mp;
      float a0=0.f, a1=0.f, asum=0.f;
      #pragma unroll
      for (int i=0;i<23;i++){
        float be = bp[i];
        u32 h = hp[i*50];
        a0 += be*bflo(h); a1 += be*bfhi(h); asum += be;
      }
      if (th<2){
        float be = bp[23]; u32 h = hp[23*50];
        a0 += be*bflo(h); a1 += be*bfhi(h); asum += be;
      }
      a0 += __shfl_xor(a0,1); a1 += __shfl_xor(a1,1); asum += __shfl_xor(asum,1);
      a0 += __shfl_xor(a0,2); a1 += __shfl_xor(a1,2); asum += __shfl_xor(asum,2);
      if (th==0){
        float rs = fast_rcp(asum);
        a0 *= rs; a1 *= rs;
        sz32[bi*192+mp] = packh2(a0,a1);
        if (step==TM-1){
          cLast[(size_t)(b0+bi)*100 + 2*mp]   = a0;
          cLast[(size_t)(b0+bi)*100 + 2*mp+1] = a1;
        }
      }
    }
    __syncthreads();
    // P5: gate row g5 for both batches + in-phase LSTM pointwise via lane shuffles.
    // d read from slot (step&1), new d written to slot (step&1)^1 -> no race.
    {
      float acc0 = biasg, acc1 = biasg;
      const u32* zc0 = sz32;
      const u32* zc1 = sz32 + 192;
      const int dof = 64 + (step&1)*64;
      #pragma unroll 1
      for (int jb=0; jb<16; jb+=4){
        uint4 w[4], v[4];
        #pragma unroll
        for (int k=0;k<4;k++) w[k] = wp0[(jb+k)*1024];
        #pragma unroll
        for (int k=0;k<4;k++) v[k] = wp1[(jb+k)*1024];
        #pragma unroll
        for (int k=0;k<4;k++){
          int j = jb+k;
          uint4 zA0 = *(const uint4*)(zc0 + 4*j);
          uint4 zA1 = *(const uint4*)(zc1 + 4*j);
          acc0 = fdot2(w[k].x, zA0.x, acc0); acc0 = fdot2(w[k].y, zA0.y, acc0);
          acc0 = fdot2(w[k].z, zA0.z, acc0); acc0 = fdot2(w[k].w, zA0.w, acc0);
          acc1 = fdot2(w[k].x, zA1.x, acc1); acc1 = fdot2(w[k].y, zA1.y, acc1);
          acc1 = fdot2(w[k].z, zA1.z, acc1); acc1 = fdot2(w[k].w, zA1.w, acc1);
          uint4 zB0 = *(const uint4*)(zc0 + dof + 4*j);
          uint4 zB1 = *(const uint4*)(zc1 + dof + 4*j);
          acc0 = fdot2(v[k].x, zB0.x, acc0); acc0 = fdot2(v[k].y, zB0.y, acc0);
          acc0 = fdot2(v[k].z, zB0.z, acc0); acc0 = fdot2(v[k].w, zB0.w, acc0);
          acc1 = fdot2(v[k].x, zB1.x, acc1); acc1 = fdot2(v[k].y, zB1.y, acc1);
          acc1 = fdot2(v[k].z, zB1.z, acc1); acc1 = fdot2(v[k].w, zB1.w, acc1);
        }
      }
      // gather the 4 gates (i,f,g,o) of (bi,p5) across the 4-lane group
      float x0 = __shfl_xor(acc0,1), x1 = __shfl_xor(acc1,1);
      float lo0 = (gid&1)? x0:acc0, hi0 = (gid&1)? acc0:x0;
      float lo1 = (gid&1)? x1:acc1, hi1 = (gid&1)? acc1:x1;
      float lo0b = __shfl_xor(lo0,2), hi0b = __shfl_xor(hi0,2);
      float lo1b = __shfl_xor(lo1,2), hi1b = __shfl_xor(hi1,2);
      const bool hib = (gid>=2);              // lanes 0,1 -> bi0; lanes 2,3 -> bi1
      float ig  = hib ? lo1b : lo0;
      float fg  = hib ? hi1b : hi0;
      float gg_ = hib ? lo1  : lo0b;
      float og  = hib ? hi1  : hi0b;
      float sn = sigmoid_f(fg)*s_reg + sigmoid_f(ig)*tanh_f(gg_);
      float dn = sigmoid_f(og)*tanh_f(sn);
      s_reg = sn;
      if ((gid&1)==0){
        int bi = gid>>1;
        sq16[bi*256+p5]     = (_Float16)dn;   // q = [d|s] for P1
        sq16[bi*256+128+p5] = (_Float16)sn;
        ((_Float16*)(sz32 + bi*192 + 64 + ((step&1)^1)*64))[p5] = (_Float16)dn;
        if (step==TM-1) dT[(size_t)(b0+bi)*128+p5]=dn;
      }
    }
    __syncthreads();
  }
}

// ---------- kernel 3: skip GRU, 8 rows/block, 9 steps ----------
__global__ __launch_bounds__(256)
void gru_kernel(const u16* __restrict__ Hb, const float* __restrict__ wih,
                const float* __restrict__ whh, const float* __restrict__ bihp,
                const float* __restrict__ bhhp, float* __restrict__ hskip)
{
  __shared__ float sWih[96][101];
  __shared__ float sWhh[96][33];
  __shared__ float sxt[8][100];
  __shared__ float sh[8][33];
  const int tid = threadIdx.x;
  for (int i=tid;i<9600;i+=256){ sWih[i/100][i%100]=wih[i]; }
  for (int i=tid;i<3072;i+=256){ sWhh[i>>5][i&31]=whh[i]; }
  const int r = tid>>5, j = tid&31;
  const int rowg = blockIdx.x*8 + r;
  const int b = rowg/10, sk = rowg - b*10;
  const float b_r = bihp[j], b_z = bihp[32+j], b_n = bihp[64+j];
  const float hb_r = bhhp[j], hb_z = bhhp[32+j], hb_n = bhhp[64+j];
  sh[r][j]=0.f;
  float h = 0.f;
  __syncthreads();
  for (int pt=0; pt<9; pt++){
    for (int i=tid;i<800;i+=256){
      int rr=i/100, m=i-rr*100;
      int rg = blockIdx.x*8+rr; int bb=rg/10, ss=rg-bb*10;
      sxt[rr][m] = bf2f(Hb[(size_t)bb*9400 + (size_t)(4+pt*10+ss)*100 + m]);
    }
    __syncthreads();
    float gi_r=b_r, gi_z=b_z, gi_n=b_n, gh_r=hb_r, gh_z=hb_z, gh_n=hb_n;
    #pragma unroll 4
    for (int m=0;m<100;m++){
      float x = sxt[r][m];
      gi_r += sWih[j][m]*x; gi_z += sWih[32+j][m]*x; gi_n += sWih[64+j][m]*x;
    }
    #pragma unroll
    for (int k=0;k<32;k++){
      float hp = sh[r][k];
      gh_r += sWhh[j][k]*hp; gh_z += sWhh[32+j][k]*hp; gh_n += sWhh[64+j][k]*hp;
    }
    float rg_ = sigmoid_f(gi_r+gh_r);
    float z  = sigmoid_f(gi_z+gh_z);
    float n  = tanh_f(gi_n + rg_*gh_n);
    h = (1.f-z)*n + z*h;
    __syncthreads();
    sh[r][j]=h;
    __syncthreads();
  }
  hskip[(size_t)b*320 + sk*32 + j] = h;
}

// ---------- kernel 4: output MLP head, 32 batches/block, w1 tiled via LDS ----------
#define OUT_NB 32
#define OUT_LDS ((OUT_NB*552 + 8*552)*4)   // 88320 bytes

__global__ __launch_bounds__(256)
void out_kernel(const float* __restrict__ dT, const float* __restrict__ cLast,
                const float* __restrict__ hskip, const float* __restrict__ w1,
                const float* __restrict__ b1, const float* __restrict__ w2,
                const float* __restrict__ b2, float* __restrict__ outp)
{
  extern __shared__ float osm[];
  float* sf = osm;                 // [32][552]
  float* sw = osm + OUT_NB*552;    // [8][552]
  const int tid = threadIdx.x;
  const int b0 = blockIdx.x*OUT_NB;
  for (int i=tid;i<OUT_NB*548;i+=256){
    int bl = i/548, k = i - 548*bl; int b = b0+bl;
    float v;
    if (k<128) v = dT[(size_t)b*128+k];
    else if (k<228) v = cLast[(size_t)b*100+(k-128)];
    else v = hskip[(size_t)b*320+(k-228)];
    sf[bl*552+k]=v;
  }
  const int bl = tid>>3, j = tid&7;
  float outv = 0.f;
  for (int jt=0; jt<128; jt+=8){
    __syncthreads();
    for (int i=tid;i<8*548;i+=256){
      int rr=i/548, c=i-548*rr;
      sw[rr*552+c] = w1[(size_t)jt*548 + i];
    }
    __syncthreads();
    float acc = b1[jt+j];
    const float* fr = sf + bl*552;
    const float* wr = sw + j*552;
    #pragma unroll 4
    for (int k=0;k<548;k++) acc += fr[k]*wr[k];
    outv += fmaxf(acc,0.f)*w2[jt+j];
  }
  outv += __shfl_xor(outv,1);
  outv += __shfl_xor(outv,2);
  outv += __shfl_xor(outv,4);
  if (j==0) outp[b0+bl] = outv + b2[0];
}

// ---------- launcher ----------
extern "C" void kernel_launch(void* const* d_in, const int* in_sizes, int n_in,
                              void* d_out, int out_size, void* d_ws, size_t ws_size,
                              hipStream_t stream)
{
  const float* enc      = (const float*)d_in[0];
  const float* conv_w   = (const float*)d_in[1];
  const float* conv_b   = (const float*)d_in[2];
  const float* Wd       = (const float*)d_in[3];
  const float* Ud       = (const float*)d_in[4];
  const float* vd       = (const float*)d_in[5];
  const float* lstm_wih = (const float*)d_in[6];
  const float* lstm_whh = (const float*)d_in[7];
  const float* lstm_bih = (const float*)d_in[8];
  const float* lstm_bhh = (const float*)d_in[9];
  const float* gru_wih  = (const float*)d_in[10];
  const float* gru_whh  = (const float*)d_in[11];
  const float* gru_bih  = (const float*)d_in[12];
  const float* gru_bhh  = (const float*)d_in[13];
  const float* out1_w   = (const float*)d_in[14];
  const float* out1_b   = (const float*)d_in[15];
  const float* out2_w   = (const float*)d_in[16];
  const float* out2_b   = (const float*)d_in[17];

  char* ws = (char*)d_ws;
  u16*   Hb    = (u16*)ws;                         // 4096*9400*2 = 77,004,800 B
  float* dT    = (float*)(ws + 77004800);          // 4096*128*4  =  2,097,152 B
  float* cLast = (float*)(ws + 79101952);          // 4096*100*4  =  1,638,400 B
  float* hskip = (float*)(ws + 80740352);          // 4096*320*4  =  5,242,880 B
  // WgT+WdT2+cwT2 alias hskip (hskip is dead until gru_kernel runs, after decoder;
  // cwT2 is dead after conv_kernel, which runs before gru)
  uint4* WgT   = (uint4*)(ws + 80740352);          // 16*1024*16  =    262,144 B
  uint4* WdT2  = (uint4*)(ws + 81002496);          //  8*512*16   =     65,536 B
  float* cwT2  = (float*)(ws + 81068032);          // 56,700*4    =    226,800 B

  prep_kernel<<<302, 256, 0, stream>>>(lstm_wih, lstm_whh, Wd, conv_w,
                                       WgT, WdT2, cwT2);

  conv_kernel<<<dim3(10,4096,1), 128, 0, stream>>>(enc, cwT2, conv_b, Hb);

  (void)hipFuncSetAttribute((const void*)decoder_kernel,
                            hipFuncAttributeMaxDynamicSharedMemorySize, DEC_LDS);
  decoder_kernel<<<4096/NB, DEC_NT, DEC_LDS, stream>>>(Hb, Ud, vd, WgT, WdT2,
                                                       lstm_bih, lstm_bhh,
                                                       dT, cLast);

  gru_kernel<<<5120, 256, 0, stream>>>(Hb, gru_wih, gru_whh, gru_bih, gru_bhh, hskip);

  (void)hipFuncSetAttribute((const void*)out_kernel,
                            hipFuncAttributeMaxDynamicSharedMemorySize, OUT_LDS);
  out_kernel<<<4096/OUT_NB, 256, OUT_LDS, stream>>>(dT, cLast, hskip, out1_w, out1_b,
                                                    out2_w, out2_b, (float*)d_out);
}

// Round 10
// 7111.061 us; speedup vs baseline: 1.3760x; 1.3760x over previous
//
#include <hip/hip_runtime.h>

typedef unsigned int u32;
typedef unsigned short u16;
typedef _Float16 half2_t __attribute__((ext_vector_type(2)));

#define TM 94          // T_MOD
#define NB 2           // batches per decoder block
#define DEC_NT 512     // 512-thread blocks: 2 independent barrier domains per CU

// ---------- helpers ----------
__device__ __forceinline__ float bf2f(u16 v){ return __builtin_bit_cast(float, ((u32)v)<<16); }
__device__ __forceinline__ float bflo(u32 v){ return __builtin_bit_cast(float, v<<16); }
__device__ __forceinline__ float bfhi(u32 v){ return __builtin_bit_cast(float, v & 0xffff0000u); }
__device__ __forceinline__ u32 f2bf_bits(float f){ u32 u=__builtin_bit_cast(u32,f); return (u + 0x7fffu + ((u>>16)&1u))>>16; }
__device__ __forceinline__ u32 packbf2(float a, float b){ return f2bf_bits(a) | (f2bf_bits(b)<<16); }
__device__ __forceinline__ u32 packh2(float a, float b){ half2_t h; h.x=(_Float16)a; h.y=(_Float16)b; return __builtin_bit_cast(u32,h); }
__device__ __forceinline__ float fdot2(u32 a, u32 b, float c){
  return __builtin_amdgcn_fdot2(__builtin_bit_cast(half2_t,a), __builtin_bit_cast(half2_t,b), c, false);
}
__device__ __forceinline__ float fast_rcp(float x){ return __builtin_amdgcn_rcpf(x); }
__device__ __forceinline__ float sigmoid_f(float x){ return fast_rcp(1.f + __expf(-x)); }
__device__ __forceinline__ float tanh_f(float x){ float e=__expf(2.f*x); return 1.f - 2.f*fast_rcp(e+1.f); }

// ---------- kernel 0: pack LSTM weights (WgT), Wd fragments (WdT2), conv weights (cwT2) ----------
// WgT[j][t] (uint4), j=0..15, t=h*512+g: h=0 wih row g (u32 k-idx u=4j+s, u<50 else 0),
//                                        h=1 whh row g (u<64).
// WdT2[i][t] (uint4), i=0..7, t=0..511: P1 fragment for thread t=(mw=t>>2, part=t&3),
//   u32 base u = part*32 + ((i+2*part)&7)*4 (bank rotation baked in). mw>=100 -> 0.
// cwT2[c][j][k] (float): conv weight transpose (contiguous block-uniform stream).
__global__ __launch_bounds__(256)
void prep_kernel(const float* __restrict__ wih, const float* __restrict__ whh,
                 const float* __restrict__ Wd, const float* __restrict__ cw,
                 uint4* __restrict__ WgT, uint4* __restrict__ WdT2,
                 float* __restrict__ cwT2)
{
  int idx = blockIdx.x*256 + threadIdx.x;   // 0..77311
  if (idx < 16384){
    int t = idx & 1023;
    int j = idx >> 10;
    int h = t >> 9, g = t & 511;
    u32 r[4];
    #pragma unroll
    for (int s=0;s<4;s++){
      int u = 4*j + s;
      u32 v = 0u;
      if (h==0){ if (u < 50) v = packh2(wih[g*100+2*u], wih[g*100+2*u+1]); }
      else     { if (u < 64) v = packh2(whh[g*128+2*u], whh[g*128+2*u+1]); }
      r[s]=v;
    }
    WgT[idx] = make_uint4(r[0],r[1],r[2],r[3]);
  } else if (idx < 20480){
    int idx2 = idx - 16384;                 // 0..4095
    int t = idx2 & 511;
    int i = idx2 >> 9;                      // 0..7
    int mw = t >> 2, part = t & 3;
    u32 r[4] = {0u,0u,0u,0u};
    if (mw < 100){
      int ii = (i + 2*part) & 7;
      const float* wd = Wd + mw*256 + 2*(part*32 + ii*4);
      #pragma unroll
      for (int k=0;k<4;k++) r[k] = packh2(wd[2*k], wd[2*k+1]);
    }
    WdT2[idx2] = make_uint4(r[0],r[1],r[2],r[3]);
  } else if (idx < 20480 + 56700){
    int idx2 = idx - 20480;                 // 0..56699
    int c = idx2 / 5670;
    int r = idx2 - c*5670;
    int j = r / 10;
    int k = r - j*10;
    cwT2[idx2] = cw[(size_t)(10*c + k)*567 + j];
  }
}

// ---------- kernel 1: conv + relu -> H (bf16) ----------
__global__ __launch_bounds__(128)
void conv_kernel(const float* __restrict__ enc, const float* __restrict__ cwT2,
                 const float* __restrict__ cb, u16* __restrict__ Hb)
{
  __shared__ float sE[8100];
  const int tid = threadIdx.x;
  const int b = blockIdx.y;
  const int chunk = blockIdx.x;      // 10 chunks of 10 m's
  const float* ep = enc + (size_t)b*8100;
  for (int i=tid;i<8100;i+=128) sE[i]=ep[i];
  __syncthreads();
  if (tid >= TM) return;
  const int t = tid;
  const int mo = chunk*10;
  const float* wb = cwT2 + chunk*5670;   // block-uniform, contiguous [j][10] stream
  float acc[10];
  #pragma unroll
  for (int k=0;k<10;k++) acc[k]=cb[mo+k];
  const float* e = sE + t*81;
  #pragma unroll 3
  for (int j=0;j<567;j++){
    float ev = e[j];
    const float* w = wb + j*10;
    #pragma unroll
    for (int k=0;k<10;k++) acc[k] += ev*w[k];
  }
  u32* out = (u32*)Hb + ((size_t)b*9400 + t*100 + mo)/2;
  #pragma unroll
  for (int k=0;k<5;k++) out[k] = packbf2(fmaxf(acc[2*k],0.f), fmaxf(acc[2*k+1],0.f));
}

// ---------- kernel 2: persistent decoder, NB=2, 512 threads, 2 blocks/CU ----------
// R10 = R8's proven decoder (coalesced P5 wp=WgT+tid, sg16 round-trip, P6 intact)
// + ONLY the P3 deletion (verified numerically safe in R9: identical absmax):
// P2 writes exp(score) (no max-subtract; |score| <= sum|vd| ~ 4), P4 carries a
// third shuffle accumulator (sum e) and self-normalizes. 6 -> 5 barriers/step,
// and the deleted phase was the worst-utilization one (128/512 threads).
// R9 LESSON (ledger): P5's lane-contiguous WgT stream is load-bearing — the
// g5 remap scattered it into 4x VMEM transactions and cost +45%. Never remap.
// VGPR pool model: waves/SIMD = floor(256/VGPR); VGPR must stay 64.
// LDS layout (bytes), NB=2:
#define OFF_SHU 37600      // sHU [2][94][50] u32 bf16-pairs
#define OFF_SQ  75200      // sq16 u32[2][128]: q=[d|s] f16 pairs (P1)
#define OFF_SZ  76224      // sz  u32[2][128]: z=[c(50)+pad(14)|d(64)] f16 pairs (P5)
#define OFF_SVD 77248      // vd fp32 [100]
#define OFF_AB  77648      // union: {sa f32[2][100]@0, sbeta f32[2][96]@800} / {sg16 f16[2][512]@0}
#define DEC_LDS 79696      // 2 x ~80KB fits 160KB -> 2 independent blocks/CU

__global__ __launch_bounds__(DEC_NT) __attribute__((amdgpu_waves_per_eu(2, 4)))
void decoder_kernel(const u16* __restrict__ Hb, const float* __restrict__ Ud,
                    const float* __restrict__ vd,
                    const uint4* __restrict__ WgT, const uint4* __restrict__ WdT2,
                    const float* __restrict__ bih, const float* __restrict__ bhh,
                    float* __restrict__ dT, float* __restrict__ cLast)
{
  extern __shared__ char smem[];
  u16*      sH   = (u16*)smem;                       // [2][94][100] bf16
  u16*      sHU  = (u16*)(smem + OFF_SHU);
  u32*      sq32 = (u32*)(smem + OFF_SQ);
  _Float16* sq16 = (_Float16*)(smem + OFF_SQ);
  u32*      sz32 = (u32*)(smem + OFF_SZ);
  _Float16* sz16 = (_Float16*)(smem + OFF_SZ);
  float*    svd  = (float*)(smem + OFF_SVD);
  float*    sa   = (float*)(smem + OFF_AB);          // live P1->P2
  float*    sbeta= (float*)(smem + OFF_AB + 800);    // e-values, live P2->P4
  _Float16* sg16 = (_Float16*)(smem + OFF_AB);       // live P5->P6 (aliases sa/sbeta; barrier-separated)

  const int tid = threadIdx.x;
  const int b0 = blockIdx.x * NB;

  // stage H (2 batches): 2350 uint4
  {
    const uint4* src = (const uint4*)(Hb + (size_t)b0*9400);
    uint4* dst = (uint4*)sH;
    for (int i=tid;i<2350;i+=DEC_NT) dst[i]=src[i];
  }
  if (tid < 100) svd[tid] = vd[tid];
  for (int i=tid;i<NB*128;i+=DEC_NT){ sq32[i]=0u; sz32[i]=0u; }
  __syncthreads();

  // HU[bi][t][k] = sum_m H[bi][t][m] * Ud[k][m]
  for (int idx=tid; idx<4700; idx+=DEC_NT){
    int kq = idx/188;                 // k-quad 0..24
    int r  = idx - kq*188;            // 0..187
    int bi = r/94;
    int t  = r - 94*bi;
    const u32* hrow = (const u32*)sH + bi*4700 + t*50;
    const float* ud0 = Ud + (kq*4+0)*100;
    const float* ud1 = Ud + (kq*4+1)*100;
    const float* ud2 = Ud + (kq*4+2)*100;
    const float* ud3 = Ud + (kq*4+3)*100;
    float c0=0.f,c1=0.f,c2=0.f,c3=0.f;
    #pragma unroll 5
    for (int mq=0; mq<25; mq++){
      uint2 hp = *(const uint2*)(hrow + mq*2);
      float h0=bflo(hp.x), h1=bfhi(hp.x), h2=bflo(hp.y), h3=bfhi(hp.y);
      float4 u0 = *(const float4*)(ud0 + mq*4);
      float4 u1 = *(const float4*)(ud1 + mq*4);
      float4 u2 = *(const float4*)(ud2 + mq*4);
      float4 u3 = *(const float4*)(ud3 + mq*4);
      c0 += h0*u0.x + h1*u0.y + h2*u0.z + h3*u0.w;
      c1 += h0*u1.x + h1*u1.y + h2*u1.z + h3*u1.w;
      c2 += h0*u2.x + h1*u2.y + h2*u2.z + h3*u2.w;
      c3 += h0*u3.x + h1*u3.y + h2*u3.z + h3*u3.w;
    }
    u32* dst = (u32*)sHU + bi*4700 + t*50 + kq*2;
    dst[0] = packbf2(c0,c1);
    dst[1] = packbf2(c2,c3);
  }
  __syncthreads();

  // P1 geometry: 4 lanes per Wd row, fragments PERSISTENT in registers (32 VGPR)
  const int mw = tid>>2, part = tid&3;
  uint4 wv[8];
  if (mw < 100){
    #pragma unroll
    for (int i=0;i<8;i++) wv[i] = WdT2[i*512 + tid];
  }
  // P5: each thread owns gate g=tid (full wih+whh rows, both batches) — COALESCED
  const float biasg = bih[tid] + bhh[tid];
  const uint4* wp0 = WgT + tid;         // wih rows (h=0 region)
  const uint4* wp1 = WgT + 512 + tid;   // whh rows (h=1 region)

  float s_reg = 0.f;                 // LSTM cell state (threads tid<256)

  #pragma unroll 1
  for (int step=0; step<TM; step++){
    // P1: a[bi][m] = q[bi] . Wd[m]  (4 lanes per row, rotated chunks for banks)
    if (mw < 100){
      #pragma unroll 1
      for (int bi=0;bi<NB;bi++){
        const u32* qb = sq32 + bi*128 + part*32;
        float a0=0.f, a1=0.f;
        #pragma unroll
        for (int i=0;i<8;i++){
          int ii = (i+2*part)&7;
          uint4 qv = *(const uint4*)(qb + ii*4);
          a0 = fdot2(wv[i].x, qv.x, a0);
          a1 = fdot2(wv[i].y, qv.y, a1);
          a0 = fdot2(wv[i].z, qv.z, a0);
          a1 = fdot2(wv[i].w, qv.w, a1);
        }
        float acc = a0+a1;
        acc += __shfl_xor(acc,1);
        acc += __shfl_xor(acc,2);
        if (part==0) sa[bi*100+mw]=acc;
      }
    }
    __syncthreads();
    // P2: e[bi][t] = exp(score) — no max-subtract (bounded scores, R9-verified);
    // 2 threads/row.
    if (tid < NB*188){
      int row = tid>>1, th = tid&1;
      int bi = row/94;
      int t  = row - 94*bi;
      const uint4* hu4 = (const uint4*)((const u32*)sHU + bi*4700 + t*50 + th*24);
      const float4* ap = (const float4*)(sa + bi*100) + th*12;
      const float4* vp = (const float4*)svd + th*12;
      float acc=0.f;
      #pragma unroll
      for (int c=0;c<6;c++){
        uint4 h4 = hu4[c];
        float4 a0 = ap[2*c], a1 = ap[2*c+1];
        float4 v0 = vp[2*c], v1 = vp[2*c+1];
        acc += v0.x*tanh_f(a0.x + bflo(h4.x));
        acc += v0.y*tanh_f(a0.y + bfhi(h4.x));
        acc += v0.z*tanh_f(a0.z + bflo(h4.y));
        acc += v0.w*tanh_f(a0.w + bfhi(h4.y));
        acc += v1.x*tanh_f(a1.x + bflo(h4.z));
        acc += v1.y*tanh_f(a1.y + bfhi(h4.z));
        acc += v1.z*tanh_f(a1.z + bflo(h4.w));
        acc += v1.w*tanh_f(a1.w + bfhi(h4.w));
      }
      if (th){ // tail m=96..99
        uint2 ht = *(const uint2*)((const u32*)hu4 + 24);
        float4 a = ap[12]; float4 v = vp[12];
        acc += v.x*tanh_f(a.x + bflo(ht.x));
        acc += v.y*tanh_f(a.y + bfhi(ht.x));
        acc += v.z*tanh_f(a.z + bflo(ht.y));
        acc += v.w*tanh_f(a.w + bfhi(ht.y));
      }
      acc += __shfl_xor(acc,1);
      if (!th) sbeta[bi*96+t]=__expf(acc);
    }
    __syncthreads();
    // P4: c[bi][m] = (sum_t e_t*H)/(sum_t e_t); third shuffle accumulator
    // replaces the deleted P3 softmax phase. 4 threads per (bi,m-pair).
    if (tid < NB*200){
      int bi = tid/200;
      int r  = tid - 200*bi;
      int mp = r>>2, th = r&3;
      int tstart = (th<2) ? th*24 : 48+(th-2)*23;
      const float* bp = sbeta + bi*96 + tstart;
      const u32* hp = (const u32*)sH + bi*4700 + tstart*50 + mp;
      float a0=0.f, a1=0.f, asum=0.f;
      #pragma unroll
      for (int i=0;i<23;i++){
        float be = bp[i];
        u32 h = hp[i*50];
        a0 += be*bflo(h); a1 += be*bfhi(h); asum += be;
      }
      if (th<2){
        float be = bp[23]; u32 h = hp[23*50];
        a0 += be*bflo(h); a1 += be*bfhi(h); asum += be;
      }
      a0 += __shfl_xor(a0,1); a1 += __shfl_xor(a1,1); asum += __shfl_xor(asum,1);
      a0 += __shfl_xor(a0,2); a1 += __shfl_xor(a1,2); asum += __shfl_xor(asum,2);
      if (th==0){
        float rs = fast_rcp(asum);
        a0 *= rs; a1 *= rs;
        sz32[bi*128+mp] = packh2(a0,a1);
        if (step==TM-1){
          cLast[(size_t)(b0+bi)*100 + 2*mp]   = a0;
          cLast[(size_t)(b0+bi)*100 + 2*mp+1] = a1;
        }
      }
    }
    __syncthreads();
    // P5: FULL gate g=tid for both batches; COALESCED WgT stream, 4-deep.
    // z reads are wave-uniform -> LDS broadcast.
    {
      float acc0 = biasg, acc1 = biasg;
      const u32* zc0 = sz32;
      const u32* zc1 = sz32 + 128;
      #pragma unroll 1
      for (int jb=0; jb<16; jb+=4){
        uint4 w[4], v[4];
        #pragma unroll
        for (int k=0;k<4;k++) w[k] = wp0[(jb+k)*1024];
        #pragma unroll
        for (int k=0;k<4;k++) v[k] = wp1[(jb+k)*1024];
        #pragma unroll
        for (int k=0;k<4;k++){
          int j = jb+k;
          uint4 zA0 = *(const uint4*)(zc0 + 4*j);
          uint4 zA1 = *(const uint4*)(zc1 + 4*j);
          acc0 = fdot2(w[k].x, zA0.x, acc0); acc0 = fdot2(w[k].y, zA0.y, acc0);
          acc0 = fdot2(w[k].z, zA0.z, acc0); acc0 = fdot2(w[k].w, zA0.w, acc0);
          acc1 = fdot2(w[k].x, zA1.x, acc1); acc1 = fdot2(w[k].y, zA1.y, acc1);
          acc1 = fdot2(w[k].z, zA1.z, acc1); acc1 = fdot2(w[k].w, zA1.w, acc1);
          uint4 zB0 = *(const uint4*)(zc0 + 64 + 4*j);
          uint4 zB1 = *(const uint4*)(zc1 + 64 + 4*j);
          acc0 = fdot2(v[k].x, zB0.x, acc0); acc0 = fdot2(v[k].y, zB0.y, acc0);
          acc0 = fdot2(v[k].z, zB0.z, acc0); acc0 = fdot2(v[k].w, zB0.w, acc0);
          acc1 = fdot2(v[k].x, zB1.x, acc1); acc1 = fdot2(v[k].y, zB1.y, acc1);
          acc1 = fdot2(v[k].z, zB1.z, acc1); acc1 = fdot2(v[k].w, zB1.w, acc1);
        }
      }
      sg16[      tid] = (_Float16)acc0;
      sg16[512 + tid] = (_Float16)acc1;
    }
    __syncthreads();
    // P6: LSTM pointwise update (tid<256: 2 bi x 128 p); s in register
    if (tid < 128*NB){
      int bi = tid>>7, p = tid&127;
      float ig = (float)sg16[bi*512+p];
      float fg = (float)sg16[bi*512+128+p];
      float gg_= (float)sg16[bi*512+256+p];
      float og = (float)sg16[bi*512+384+p];
      float sn = sigmoid_f(fg)*s_reg + sigmoid_f(ig)*tanh_f(gg_);
      float dn = sigmoid_f(og)*tanh_f(sn);
      s_reg = sn;
      sq16[bi*256+p]      = (_Float16)dn;   // q = [d|s] for P1
      sq16[bi*256+128+p]  = (_Float16)sn;
      sz16[bi*256+128+p]  = (_Float16)dn;   // z = [c|d] for P5
      if (step==TM-1) dT[(size_t)(b0+bi)*128+p]=dn;
    }
    __syncthreads();
  }
}

// ---------- kernel 3: skip GRU, 8 rows/block, 9 steps ----------
__global__ __launch_bounds__(256)
void gru_kernel(const u16* __restrict__ Hb, const float* __restrict__ wih,
                const float* __restrict__ whh, const float* __restrict__ bihp,
                const float* __restrict__ bhhp, float* __restrict__ hskip)
{
  __shared__ float sWih[96][101];
  __shared__ float sWhh[96][33];
  __shared__ float sxt[8][100];
  __shared__ float sh[8][33];
  const int tid = threadIdx.x;
  for (int i=tid;i<9600;i+=256){ sWih[i/100][i%100]=wih[i]; }
  for (int i=tid;i<3072;i+=256){ sWhh[i>>5][i&31]=whh[i]; }
  const int r = tid>>5, j = tid&31;
  const int rowg = blockIdx.x*8 + r;
  const int b = rowg/10, sk = rowg - b*10;
  const float b_r = bihp[j], b_z = bihp[32+j], b_n = bihp[64+j];
  const float hb_r = bhhp[j], hb_z = bhhp[32+j], hb_n = bhhp[64+j];
  sh[r][j]=0.f;
  float h = 0.f;
  __syncthreads();
  for (int pt=0; pt<9; pt++){
    for (int i=tid;i<800;i+=256){
      int rr=i/100, m=i-rr*100;
      int rg = blockIdx.x*8+rr; int bb=rg/10, ss=rg-bb*10;
      sxt[rr][m] = bf2f(Hb[(size_t)bb*9400 + (size_t)(4+pt*10+ss)*100 + m]);
    }
    __syncthreads();
    float gi_r=b_r, gi_z=b_z, gi_n=b_n, gh_r=hb_r, gh_z=hb_z, gh_n=hb_n;
    #pragma unroll 4
    for (int m=0;m<100;m++){
      float x = sxt[r][m];
      gi_r += sWih[j][m]*x; gi_z += sWih[32+j][m]*x; gi_n += sWih[64+j][m]*x;
    }
    #pragma unroll
    for (int k=0;k<32;k++){
      float hp = sh[r][k];
      gh_r += sWhh[j][k]*hp; gh_z += sWhh[32+j][k]*hp; gh_n += sWhh[64+j][k]*hp;
    }
    float rg_ = sigmoid_f(gi_r+gh_r);
    float z  = sigmoid_f(gi_z+gh_z);
    float n  = tanh_f(gi_n + rg_*gh_n);
    h = (1.f-z)*n + z*h;
    __syncthreads();
    sh[r][j]=h;
    __syncthreads();
  }
  hskip[(size_t)b*320 + sk*32 + j] = h;
}

// ---------- kernel 4: output MLP head, 32 batches/block, w1 tiled via LDS ----------
#define OUT_NB 32
#define OUT_LDS ((OUT_NB*552 + 8*552)*4)   // 88320 bytes

__global__ __launch_bounds__(256)
void out_kernel(const float* __restrict__ dT, const float* __restrict__ cLast,
                const float* __restrict__ hskip, const float* __restrict__ w1,
                const float* __restrict__ b1, const float* __restrict__ w2,
                const float* __restrict__ b2, float* __restrict__ outp)
{
  extern __shared__ float osm[];
  float* sf = osm;                 // [32][552]
  float* sw = osm + OUT_NB*552;    // [8][552]
  const int tid = threadIdx.x;
  const int b0 = blockIdx.x*OUT_NB;
  for (int i=tid;i<OUT_NB*548;i+=256){
    int bl = i/548, k = i - 548*bl; int b = b0+bl;
    float v;
    if (k<128) v = dT[(size_t)b*128+k];
    else if (k<228) v = cLast[(size_t)b*100+(k-128)];
    else v = hskip[(size_t)b*320+(k-228)];
    sf[bl*552+k]=v;
  }
  const int bl = tid>>3, j = tid&7;
  float outv = 0.f;
  for (int jt=0; jt<128; jt+=8){
    __syncthreads();
    for (int i=tid;i<8*548;i+=256){
      int rr=i/548, c=i-548*rr;
      sw[rr*552+c] = w1[(size_t)jt*548 + i];
    }
    __syncthreads();
    float acc = b1[jt+j];
    const float* fr = sf + bl*552;
    const float* wr = sw + j*552;
    #pragma unroll 4
    for (int k=0;k<548;k++) acc += fr[k]*wr[k];
    outv += fmaxf(acc,0.f)*w2[jt+j];
  }
  outv += __shfl_xor(outv,1);
  outv += __shfl_xor(outv,2);
  outv += __shfl_xor(outv,4);
  if (j==0) outp[b0+bl] = outv + b2[0];
}

// ---------- launcher ----------
extern "C" void kernel_launch(void* const* d_in, const int* in_sizes, int n_in,
                              void* d_out, int out_size, void* d_ws, size_t ws_size,
                              hipStream_t stream)
{
  const float* enc      = (const float*)d_in[0];
  const float* conv_w   = (const float*)d_in[1];
  const float* conv_b   = (const float*)d_in[2];
  const float* Wd       = (const float*)d_in[3];
  const float* Ud       = (const float*)d_in[4];
  const float* vd       = (const float*)d_in[5];
  const float* lstm_wih = (const float*)d_in[6];
  const float* lstm_whh = (const float*)d_in[7];
  const float* lstm_bih = (const float*)d_in[8];
  const float* lstm_bhh = (const float*)d_in[9];
  const float* gru_wih  = (const float*)d_in[10];
  const float* gru_whh  = (const float*)d_in[11];
  const float* gru_bih  = (const float*)d_in[12];
  const float* gru_bhh  = (const float*)d_in[13];
  const float* out1_w   = (const float*)d_in[14];
  const float* out1_b   = (const float*)d_in[15];
  const float* out2_w   = (const float*)d_in[16];
  const float* out2_b   = (const float*)d_in[17];

  char* ws = (char*)d_ws;
  u16*   Hb    = (u16*)ws;                         // 4096*9400*2 = 77,004,800 B
  float* dT    = (float*)(ws + 77004800);          // 4096*128*4  =  2,097,152 B
  float* cLast = (float*)(ws + 79101952);          // 4096*100*4  =  1,638,400 B
  float* hskip = (float*)(ws + 80740352);          // 4096*320*4  =  5,242,880 B
  // WgT+WdT2+cwT2 alias hskip (hskip is dead until gru_kernel runs, after decoder;
  // cwT2 is dead after conv_kernel, which runs before gru)
  uint4* WgT   = (uint4*)(ws + 80740352);          // 16*1024*16  =    262,144 B
  uint4* WdT2  = (uint4*)(ws + 81002496);          //  8*512*16   =     65,536 B
  float* cwT2  = (float*)(ws + 81068032);          // 56,700*4    =    226,800 B

  prep_kernel<<<302, 256, 0, stream>>>(lstm_wih, lstm_whh, Wd, conv_w,
                                       WgT, WdT2, cwT2);

  conv_kernel<<<dim3(10,4096,1), 128, 0, stream>>>(enc, cwT2, conv_b, Hb);

  (void)hipFuncSetAttribute((const void*)decoder_kernel,
                            hipFuncAttributeMaxDynamicSharedMemorySize, DEC_LDS);
  decoder_kernel<<<4096/NB, DEC_NT, DEC_LDS, stream>>>(Hb, Ud, vd, WgT, WdT2,
                                                       lstm_bih, lstm_bhh,
                                                       dT, cLast);

  gru_kernel<<<5120, 256, 0, stream>>>(Hb, gru_wih, gru_whh, gru_bih, gru_bhh, hskip);

  (void)hipFuncSetAttribute((const void*)out_kernel,
                            hipFuncAttributeMaxDynamicSharedMemorySize, OUT_LDS);
  out_kernel<<<4096/OUT_NB, 256, OUT_LDS, stream>>>(dT, cLast, hskip, out1_w, out1_b,
                                                    out2_w, out2_b, (float*)d_out);
}